// Round 7
// baseline (243.764 us; speedup 1.0000x reference)
//
#include <hip/hip_runtime.h>
#include <hip/hip_bf16.h>

#define S49 49
#define D128 128
#define NH 4

typedef __attribute__((ext_vector_type(8))) short short8;
typedef __attribute__((ext_vector_type(4))) short short4v;
typedef __attribute__((ext_vector_type(4))) float f32x4;

__device__ __forceinline__ unsigned short f2b(float x){
  unsigned u = __builtin_bit_cast(unsigned, x);
  return (unsigned short)((u + 0x7fffu + ((u>>16)&1u)) >> 16);   // RNE
}
__device__ __forceinline__ unsigned pk2(float a, float b){
  __hip_bfloat162 h = __float22bfloat162_rn(float2{a, b});      // HW v_cvt_pk_bf16_f32
  unsigned u; __builtin_memcpy(&u, &h, 4);
  return u;
}
// XOR-swizzled LDS indexing (ushort units), 16B granule: conflict-free
// fragment reads at power-of-2 strides, no padding.
__device__ __forceinline__ int swz256i(int row, int col){  // 128-elem (256B) rows
  return row*128 + ((((col>>3) ^ (row&15)) << 3) | (col&7));
}

// ---- K0: transpose weights to Wt[mat][n][k] bf16 in workspace ----
__global__ void prep_wt(const float* __restrict__ Wq, const float* __restrict__ Wk,
                        const float* __restrict__ Wv, unsigned short* __restrict__ wt){
  int e = blockIdx.x*256 + threadIdx.x;
  if (e >= 3*128*128) return;
  int mat = e >> 14, rem = e & 16383, n = rem >> 7, k = rem & 127;
  const float* W = (mat==0) ? Wq : ((mat==1) ? Wk : Wv);
  wt[e] = f2b(W[k*128 + n]);
}

// ---- K1: combined (mask + rel-pos-bias) table, PRE-SCALED by log2(e), float4-swizzled ----
// comb4[(((w*NH+h)*49)+i)*16 + ln] = { c(i,ln), c(i,16+ln), c(i,32+ln), c(i,48+ln) } * log2e
// pad (j>=49) = -1e30 so exp2 -> 0 exactly.
__global__ void prep_comb(const float* __restrict__ mask, const float* __restrict__ bt,
                          float4* __restrict__ comb4, int nW){
  int e = blockIdx.x*256 + threadIdx.x;
  if (e >= nW*NH*S49*16) return;
  int ln = e & 15; int t = e >> 4;
  int i = t % S49; t /= S49;
  int h = t & (NH-1); int w = t / NH;
  const float* mrow = mask + ((size_t)w*S49 + i)*S49;
  int ri = i/7, ci = i - ri*7;
  const float L2E = 1.4426950408889634f;
  float v[4];
  #pragma unroll
  for (int nt = 0; nt < 4; ++nt){
    int j = nt*16 + ln;
    if (j < S49){
      int rj = j/7, cj = j - rj*7;
      int idx = (ri - rj + 6)*13 + (ci - cj + 6);
      v[nt] = (mrow[j] + bt[idx*NH + h]) * L2E;
    } else v[nt] = -1e30f;
  }
  float4 o; o.x = v[0]; o.y = v[1]; o.z = v[2]; o.w = v[3];
  comb4[e] = o;
}

// ---- main fused kernel: one block (8 waves) per window, 2 barriers, 3 blocks/CU ----
// wave = (row-tile rt = wave&3, head-pair hp = wave>>2)
__global__ __launch_bounds__(512, 6) void swin_attn(
    const float* __restrict__ hs,
    const float* __restrict__ bq, const float* __restrict__ bk,
    const float* __restrict__ bv,
    const float4* __restrict__ comb4,
    const unsigned short* __restrict__ wt, float* __restrict__ out, int nW){

  // 53664 B (rounds to 53760): hs/P 12544 | q 12544 | k 12544 | vt 14336 | pext 1696
  __shared__ __align__(16) unsigned short lds[26832];
  unsigned short* hs_s = lds;              // 49x128 swz256i; dead after proj -> P tiles waves 0..6
  unsigned short* q_s  = lds + 6272;       // 49x128 swz256i
  unsigned short* k_s  = lds + 12544;      // 49x128 swz256i (QK tile-3 rows reg-masked)
  unsigned short* vt_s = lds + 18816;      // 128x56 LINEAR (cols 49..55 zeroed; stride 112B = 2-way free)
  unsigned short* pext = lds + 25984;      // wave 7's P tile (+ overflow pad)

  const int b = blockIdx.x;
  const int tid = threadIdx.x;
  const int wave = tid >> 6, lane = tid & 63;
  const int lg = lane >> 4, ln = lane & 15;
  unsigned short* pp = (wave < 7) ? (hs_s + wave*832) : pext;   // 16x52 linear per wave

  // ---- stage hidden_states f32 -> bf16 LDS ----
  const float* hsb = hs + (size_t)b * (S49*D128);
  #pragma unroll
  for (int it = 0; it < 4; ++it) {
    int u = tid + it*512;                  // 1568 units of 4 f32
    if (u < S49*32) {
      int row = u >> 5, c = u & 31;
      float4 f = *(const float4*)(hsb + row*128 + c*4);
      uint2 o; o.x = pk2(f.x, f.y); o.y = pk2(f.z, f.w);
      *(uint2*)&hs_s[swz256i(row, c*4)] = o;
    }
  }
  // zero vt pad cols 49..55 (finite guarantee for PV's B-operand)
  #pragma unroll
  for (int it = 0; it < 2; ++it) {
    int u = tid + it*512;
    if (u < 128*7) {
      int r = u/7, c = 49 + (u - r*7);
      vt_s[r*56 + c] = 0;
    }
  }
  __syncthreads();

  const int w = b % nW;
  const int rt = wave & 3, hp = wave >> 2;
  const int mbw = (rt<3) ? rt*16 : 33;     // wave's q-row tile (overlap rows recompute identically)

  // ---- QKV projection: wave owns 16 output cols of EACH of the 3 matrices ----
  {
    const int ntb = wave*16;
    short8 a[3][4];
    #pragma unroll
    for (int mat = 0; mat < 3; ++mat)
      #pragma unroll
      for (int ks = 0; ks < 4; ++ks)
        a[mat][ks] = *(const short8*)&wt[(mat<<14) + (ntb+ln)*128 + ks*32 + lg*8];
    float4 bias_q = *(const float4*)&bq[ntb + 4*lg];
    float4 bias_k = *(const float4*)&bk[ntb + 4*lg];
    float4 bias_v = *(const float4*)&bv[ntb + 4*lg];
    #pragma unroll
    for (int mt = 0; mt < 4; ++mt) {
      const int mb = (mt<3) ? mt*16 : 33;        // overlapping tiles cover rows 0..48
      short8 bh[4];
      #pragma unroll
      for (int ks = 0; ks < 4; ++ks)
        bh[ks] = *(const short8*)&hs_s[swz256i(mb+ln, ks*32 + lg*8)];
      #pragma unroll
      for (int mat = 0; mat < 3; ++mat) {
        f32x4 acc = {0.f,0.f,0.f,0.f};
        #pragma unroll
        for (int ks = 0; ks < 4; ++ks)
          acc = __builtin_amdgcn_mfma_f32_16x16x32_bf16(a[mat][ks], bh[ks], acc, 0,0,0);
        // D transposed: col(ln) = token row m, rows(4lg+r) = output col n
        const int m = mb + ln;
        const int nb = ntb + 4*lg;
        if (mat == 0) {
          uint2 o; o.x = pk2(acc[0]+bias_q.x, acc[1]+bias_q.y);
                   o.y = pk2(acc[2]+bias_q.z, acc[3]+bias_q.w);
          *(uint2*)&q_s[swz256i(m, nb)] = o;
        } else if (mat == 1) {
          uint2 o; o.x = pk2(acc[0]+bias_k.x, acc[1]+bias_k.y);
                   o.y = pk2(acc[2]+bias_k.z, acc[3]+bias_k.w);
          *(uint2*)&k_s[swz256i(m, nb)] = o;
        } else {
          vt_s[(nb+0)*56 + m] = f2b(acc[0]+bias_v.x);
          vt_s[(nb+1)*56 + m] = f2b(acc[1]+bias_v.y);
          vt_s[(nb+2)*56 + m] = f2b(acc[2]+bias_v.z);
          vt_s[(nb+3)*56 + m] = f2b(acc[3]+bias_v.w);
        }
      }
    }
  }

  // prefetch both heads' combined bias rows; latency drains under the barrier
  float4 cb[2][4];
  #pragma unroll
  for (int hh = 0; hh < 2; ++hh)
    #pragma unroll
    for (int r = 0; r < 4; ++r)
      cb[hh][r] = comb4[((size_t)(w*NH + hp*2 + hh)*S49 + mbw + 4*lg + r)*16 + ln];

  __syncthreads();
  // ---- attention: NO barriers (P wave-private; q/k/vt read-only; pp aliases dead hs) ----

  const float C1 = 0.17677669529663687f * 1.4426950408889634f;  // scale * log2e
  const short8 ones = {16256,16256,16256,16256,16256,16256,16256,16256};  // bf16 1.0
  const short4v z4 = {0,0,0,0};

  #pragma unroll
  for (int hh = 0; hh < 2; ++hh) {
    const int h = hp*2 + hh;

    // ---- QK^T: k-tiles {0,16,32,48}; scores stay in registers ----
    short8 aq = *(const short8*)&q_s[swz256i(mbw+ln, h*32 + lg*8)];
    short8 kb[4];
    #pragma unroll
    for (int nt = 0; nt < 4; ++nt)
      kb[nt] = *(const short8*)&k_s[swz256i(nt*16+ln, h*32 + lg*8)];  // nt=3 ln>0: garbage rows
    if (ln != 0) kb[3] = short8{0,0,0,0,0,0,0,0};                     // only k-row 48 is real
    f32x4 s[4];
    __builtin_amdgcn_s_setprio(1);
    #pragma unroll
    for (int nt = 0; nt < 4; ++nt) {
      f32x4 z = {0.f,0.f,0.f,0.f};
      s[nt] = __builtin_amdgcn_mfma_f32_16x16x32_bf16(aq, kb[nt], z, 0,0,0);
    }
    __builtin_amdgcn_s_setprio(0);

    // ---- max-free softmax numerator; pad cols produce exactly 0 ----
    // lane holds q-rows (mbw+4lg+r), k = 16nt+ln
    #pragma unroll
    for (int r = 0; r < 4; ++r) {
      float cbv[4] = {cb[hh][r].x, cb[hh][r].y, cb[hh][r].z, cb[hh][r].w};
      #pragma unroll
      for (int nt = 0; nt < 4; ++nt) {
        float e = exp2f(fmaf(s[nt][r], C1, cbv[nt]));
        if (nt < 3 || ln < 4)                       // P is 52 cols wide
          pp[(4*lg + r)*52 + nt*16 + ln] = f2b(e);
      }
    }

    // ---- P A-fragments (rows=q, k-cols) with pad masking ----
    short4v a0 = *(const short4v*)&pp[ln*52 + lg*8];
    short4v a1 = *(const short4v*)&pp[ln*52 + lg*8 + 4];
    short8 ap0 = __builtin_shufflevector(a0, a1, 0,1,2,3,4,5,6,7);
    short4v b0 = *(const short4v*)&pp[ln*52 + 32 + lg*8];
    short4v b1 = *(const short4v*)&pp[ln*52 + 36 + lg*8];
    if (lg >= 2) b1 = z4;                           // k 52..55 (garbage) / 60..63
    if (lg == 3) b0 = z4;                           // k 56..59
    short8 ap1 = __builtin_shufflevector(b0, b1, 0,1,2,3,4,5,6,7);

    // ---- row-sum via P @ ones (overlaps PV), then P @ V; normalize at store ----
    f32x4 sacc = {0.f,0.f,0.f,0.f};
    __builtin_amdgcn_s_setprio(1);
    sacc = __builtin_amdgcn_mfma_f32_16x16x32_bf16(ap0, ones, sacc, 0,0,0);
    sacc = __builtin_amdgcn_mfma_f32_16x16x32_bf16(ap1, ones, sacc, 0,0,0);
    __builtin_amdgcn_s_setprio(0);
    float inv[4];
    #pragma unroll
    for (int r = 0; r < 4; ++r) inv[r] = __builtin_amdgcn_rcpf(sacc[r]);

    #pragma unroll
    for (int nt = 0; nt < 2; ++nt) {
      const int vr = h*32 + nt*16 + ln;             // output col == vt row
      short8 bv0 = *(const short8*)&vt_s[vr*56 + lg*8];
      short8 bv1 = {0,0,0,0,0,0,0,0};
      if (lg < 3) bv1 = *(const short8*)&vt_s[vr*56 + 32 + lg*8];  // lg=3 k>=56: masked (no NaN)
      f32x4 acc = {0.f,0.f,0.f,0.f};
      __builtin_amdgcn_s_setprio(1);
      acc = __builtin_amdgcn_mfma_f32_16x16x32_bf16(ap0, bv0, acc, 0,0,0);
      acc = __builtin_amdgcn_mfma_f32_16x16x32_bf16(ap1, bv1, acc, 0,0,0);
      __builtin_amdgcn_s_setprio(0);
      const int mr = mbw + 4*lg;
      #pragma unroll
      for (int r = 0; r < 4; ++r)
        out[((size_t)b*S49 + mr + r)*D128 + vr] = acc[r]*inv[r];
    }
  }
}

extern "C" void kernel_launch(void* const* d_in, const int* in_sizes, int n_in,
                              void* d_out, int out_size, void* d_ws, size_t ws_size,
                              hipStream_t stream){
  const float* hs  = (const float*)d_in[0];
  const float* msk = (const float*)d_in[1];
  const float* Wq  = (const float*)d_in[2];
  const float* bq  = (const float*)d_in[3];
  const float* Wk  = (const float*)d_in[4];
  const float* bk  = (const float*)d_in[5];
  const float* Wv  = (const float*)d_in[6];
  const float* bv  = (const float*)d_in[7];
  const float* bt  = (const float*)d_in[8];
  unsigned short* wt = (unsigned short*)d_ws;
  float4* comb4 = (float4*)((char*)d_ws + 98304);
  float* out = (float*)d_out;
  const int B  = in_sizes[0] / (S49*D128);
  const int nW = in_sizes[1] / (S49*S49);
  prep_wt<<<dim3((3*128*128 + 255)/256), dim3(256), 0, stream>>>(Wq, Wk, Wv, wt);
  prep_comb<<<dim3((nW*NH*S49*16 + 255)/256), dim3(256), 0, stream>>>(msk, bt, comb4, nW);
  swin_attn<<<dim3(B), dim3(512), 0, stream>>>(hs, bq, bk, bv, comb4, wt, out, nW);
}

// Round 8
// 105.116 us; speedup vs baseline: 2.3190x; 2.3190x over previous
//
#include <hip/hip_runtime.h>
#include <hip/hip_bf16.h>

#define S49 49
#define D128 128
#define NH 4

typedef __attribute__((ext_vector_type(8))) short short8;
typedef __attribute__((ext_vector_type(4))) short short4v;
typedef __attribute__((ext_vector_type(4))) float f32x4;

__device__ __forceinline__ unsigned short f2b(float x){
  unsigned u = __builtin_bit_cast(unsigned, x);
  return (unsigned short)((u + 0x7fffu + ((u>>16)&1u)) >> 16);   // RNE
}
__device__ __forceinline__ unsigned pk2(float a, float b){
  __hip_bfloat162 h = __float22bfloat162_rn(float2{a, b});      // HW v_cvt_pk_bf16_f32
  unsigned u; __builtin_memcpy(&u, &h, 4);
  return u;
}
// XOR-swizzled LDS indexing (ushort units), 16B granule: conflict-free
// fragment reads at power-of-2 strides, no padding.
__device__ __forceinline__ int swz256i(int row, int col){  // 128-elem (256B) rows
  return row*128 + ((((col>>3) ^ (row&15)) << 3) | (col&7));
}

// ---- K0: transpose weights to Wt[mat][n][k] bf16 in workspace ----
__global__ void prep_wt(const float* __restrict__ Wq, const float* __restrict__ Wk,
                        const float* __restrict__ Wv, unsigned short* __restrict__ wt){
  int e = blockIdx.x*256 + threadIdx.x;
  if (e >= 3*128*128) return;
  int mat = e >> 14, rem = e & 16383, n = rem >> 7, k = rem & 127;
  const float* W = (mat==0) ? Wq : ((mat==1) ? Wk : Wv);
  wt[e] = f2b(W[k*128 + n]);
}

// ---- K1: combined (mask + rel-pos-bias) table, PRE-SCALED by log2(e), float4-swizzled ----
// comb4[(((w*NH+h)*49)+i)*16 + ln] = { c(i,ln), c(i,16+ln), c(i,32+ln), c(i,48+ln) } * log2e
// pad (j>=49) = -1e30 so exp2 -> 0 exactly.
__global__ void prep_comb(const float* __restrict__ mask, const float* __restrict__ bt,
                          float4* __restrict__ comb4, int nW){
  int e = blockIdx.x*256 + threadIdx.x;
  if (e >= nW*NH*S49*16) return;
  int ln = e & 15; int t = e >> 4;
  int i = t % S49; t /= S49;
  int h = t & (NH-1); int w = t / NH;
  const float* mrow = mask + ((size_t)w*S49 + i)*S49;
  int ri = i/7, ci = i - ri*7;
  const float L2E = 1.4426950408889634f;
  float v[4];
  #pragma unroll
  for (int nt = 0; nt < 4; ++nt){
    int j = nt*16 + ln;
    if (j < S49){
      int rj = j/7, cj = j - rj*7;
      int idx = (ri - rj + 6)*13 + (ci - cj + 6);
      v[nt] = (mrow[j] + bt[idx*NH + h]) * L2E;
    } else v[nt] = -1e30f;
  }
  float4 o; o.x = v[0]; o.y = v[1]; o.z = v[2]; o.w = v[3];
  comb4[e] = o;
}

// ---- main fused kernel: one block (8 waves) per window, 2 barriers ----
// LDS 53760B -> 3 blocks/CU co-resident (161280 <= 163840); launch_bounds(,4)
// keeps compiler at ~64 VGPR (<= 512/6=85) so HW can still run 6 waves/EU.
__global__ __launch_bounds__(512, 4) void swin_attn(
    const float* __restrict__ hs,
    const float* __restrict__ bq, const float* __restrict__ bk,
    const float* __restrict__ bv,
    const float4* __restrict__ comb4,
    const unsigned short* __restrict__ wt, float* __restrict__ out, int nW){

  // 53664 B (rounds to 53760): hs/P 12544 | q 12544 | k 12544 | vt 14336 | pext 1696
  __shared__ __align__(16) unsigned short lds[26832];
  unsigned short* hs_s = lds;              // 49x128 swz256i; dead after proj -> P tiles waves 0..6
  unsigned short* q_s  = lds + 6272;       // 49x128 swz256i
  unsigned short* k_s  = lds + 12544;      // 49x128 swz256i (QK tile-3 rows reg-masked)
  unsigned short* vt_s = lds + 18816;      // 128x56 LINEAR (cols 49..55 zeroed; stride 112B = 2-way free)
  unsigned short* pext = lds + 25984;      // wave 7's P tile

  const int b = blockIdx.x;
  const int tid = threadIdx.x;
  const int wave = tid >> 6, lane = tid & 63;
  const int lg = lane >> 4, ln = lane & 15;
  unsigned short* pp = (wave < 7) ? (hs_s + wave*832) : pext;   // 16x52 linear per wave

  // ---- stage hidden_states f32 -> bf16 LDS ----
  const float* hsb = hs + (size_t)b * (S49*D128);
  #pragma unroll
  for (int it = 0; it < 4; ++it) {
    int u = tid + it*512;                  // 1568 units of 4 f32
    if (u < S49*32) {
      int row = u >> 5, c = u & 31;
      float4 f = *(const float4*)(hsb + row*128 + c*4);
      uint2 o; o.x = pk2(f.x, f.y); o.y = pk2(f.z, f.w);
      *(uint2*)&hs_s[swz256i(row, c*4)] = o;
    }
  }
  // zero vt pad cols 49..55 (finite guarantee for PV's B-operand)
  #pragma unroll
  for (int it = 0; it < 2; ++it) {
    int u = tid + it*512;
    if (u < 128*7) {
      int r = u/7, c = 49 + (u - r*7);
      vt_s[r*56 + c] = 0;
    }
  }
  __syncthreads();

  const int w = b % nW;
  const int rt = wave & 3, hp = wave >> 2;
  const int mbw = (rt<3) ? rt*16 : 33;     // wave's q-row tile (overlap rows recompute identically)

  // ---- QKV projection: wave owns 16 output cols of EACH of the 3 matrices ----
  {
    const int ntb = wave*16;
    short8 a[3][4];
    #pragma unroll
    for (int mat = 0; mat < 3; ++mat)
      #pragma unroll
      for (int ks = 0; ks < 4; ++ks)
        a[mat][ks] = *(const short8*)&wt[(mat<<14) + (ntb+ln)*128 + ks*32 + lg*8];
    float4 bias_q = *(const float4*)&bq[ntb + 4*lg];
    float4 bias_k = *(const float4*)&bk[ntb + 4*lg];
    float4 bias_v = *(const float4*)&bv[ntb + 4*lg];
    #pragma unroll
    for (int mt = 0; mt < 4; ++mt) {
      const int mb = (mt<3) ? mt*16 : 33;        // overlapping tiles cover rows 0..48
      short8 bh[4];
      #pragma unroll
      for (int ks = 0; ks < 4; ++ks)
        bh[ks] = *(const short8*)&hs_s[swz256i(mb+ln, ks*32 + lg*8)];
      #pragma unroll
      for (int mat = 0; mat < 3; ++mat) {
        f32x4 acc = {0.f,0.f,0.f,0.f};
        #pragma unroll
        for (int ks = 0; ks < 4; ++ks)
          acc = __builtin_amdgcn_mfma_f32_16x16x32_bf16(a[mat][ks], bh[ks], acc, 0,0,0);
        // D transposed: col(ln) = token row m, rows(4lg+r) = output col n
        const int m = mb + ln;
        const int nb = ntb + 4*lg;
        if (mat == 0) {
          uint2 o; o.x = pk2(acc[0]+bias_q.x, acc[1]+bias_q.y);
                   o.y = pk2(acc[2]+bias_q.z, acc[3]+bias_q.w);
          *(uint2*)&q_s[swz256i(m, nb)] = o;
        } else if (mat == 1) {
          uint2 o; o.x = pk2(acc[0]+bias_k.x, acc[1]+bias_k.y);
                   o.y = pk2(acc[2]+bias_k.z, acc[3]+bias_k.w);
          *(uint2*)&k_s[swz256i(m, nb)] = o;
        } else {
          vt_s[(nb+0)*56 + m] = f2b(acc[0]+bias_v.x);
          vt_s[(nb+1)*56 + m] = f2b(acc[1]+bias_v.y);
          vt_s[(nb+2)*56 + m] = f2b(acc[2]+bias_v.z);
          vt_s[(nb+3)*56 + m] = f2b(acc[3]+bias_v.w);
        }
      }
    }
  }
  __syncthreads();
  // ---- attention: NO barriers (P wave-private; q/k/vt read-only; pp aliases dead hs) ----

  const float C1 = 0.17677669529663687f * 1.4426950408889634f;  // scale * log2e
  const short8 ones = {16256,16256,16256,16256,16256,16256,16256,16256};  // bf16 1.0
  const short4v z4 = {0,0,0,0};

  #pragma unroll
  for (int hh = 0; hh < 2; ++hh) {
    const int h = hp*2 + hh;
    float4 cb[4];
    #pragma unroll
    for (int r = 0; r < 4; ++r)
      cb[r] = comb4[((size_t)(w*NH + h)*S49 + mbw + 4*lg + r)*16 + ln];

    // ---- QK^T: k-tiles {0,16,32,48}; scores stay in registers ----
    short8 aq = *(const short8*)&q_s[swz256i(mbw+ln, h*32 + lg*8)];
    short8 kb[4];
    #pragma unroll
    for (int nt = 0; nt < 4; ++nt)
      kb[nt] = *(const short8*)&k_s[swz256i(nt*16+ln, h*32 + lg*8)];  // nt=3 ln>0: garbage rows
    if (ln != 0) kb[3] = short8{0,0,0,0,0,0,0,0};                     // only k-row 48 is real
    f32x4 s[4];
    __builtin_amdgcn_s_setprio(1);
    #pragma unroll
    for (int nt = 0; nt < 4; ++nt) {
      f32x4 z = {0.f,0.f,0.f,0.f};
      s[nt] = __builtin_amdgcn_mfma_f32_16x16x32_bf16(aq, kb[nt], z, 0,0,0);
    }
    __builtin_amdgcn_s_setprio(0);

    // ---- max-free softmax numerator; pad cols produce exactly 0 ----
    // lane holds q-rows (mbw+4lg+r), k = 16nt+ln
    #pragma unroll
    for (int r = 0; r < 4; ++r) {
      float cbv[4] = {cb[r].x, cb[r].y, cb[r].z, cb[r].w};
      #pragma unroll
      for (int nt = 0; nt < 4; ++nt) {
        float e = exp2f(fmaf(s[nt][r], C1, cbv[nt]));
        if (nt < 3 || ln < 4)                       // P is 52 cols wide
          pp[(4*lg + r)*52 + nt*16 + ln] = f2b(e);
      }
    }

    // ---- P A-fragments (rows=q, k-cols) with pad masking ----
    short4v a0 = *(const short4v*)&pp[ln*52 + lg*8];
    short4v a1 = *(const short4v*)&pp[ln*52 + lg*8 + 4];
    short8 ap0 = __builtin_shufflevector(a0, a1, 0,1,2,3,4,5,6,7);
    short4v b0 = *(const short4v*)&pp[ln*52 + 32 + lg*8];
    short4v b1 = *(const short4v*)&pp[ln*52 + 36 + lg*8];
    if (lg >= 2) b1 = z4;                           // k 52..55 (garbage) / 60..63
    if (lg == 3) b0 = z4;                           // k 56..59
    short8 ap1 = __builtin_shufflevector(b0, b1, 0,1,2,3,4,5,6,7);

    // ---- row-sum via P @ ones, then P @ V; normalize at store ----
    f32x4 sacc = {0.f,0.f,0.f,0.f};
    __builtin_amdgcn_s_setprio(1);
    sacc = __builtin_amdgcn_mfma_f32_16x16x32_bf16(ap0, ones, sacc, 0,0,0);
    sacc = __builtin_amdgcn_mfma_f32_16x16x32_bf16(ap1, ones, sacc, 0,0,0);
    __builtin_amdgcn_s_setprio(0);
    float inv[4];
    #pragma unroll
    for (int r = 0; r < 4; ++r) inv[r] = __builtin_amdgcn_rcpf(sacc[r]);

    #pragma unroll
    for (int nt = 0; nt < 2; ++nt) {
      const int vr = h*32 + nt*16 + ln;             // output col == vt row
      short8 bv0 = *(const short8*)&vt_s[vr*56 + lg*8];
      short8 bv1 = {0,0,0,0,0,0,0,0};
      if (lg < 3) bv1 = *(const short8*)&vt_s[vr*56 + 32 + lg*8];  // lg=3 k>=56: masked (no NaN)
      f32x4 acc = {0.f,0.f,0.f,0.f};
      __builtin_amdgcn_s_setprio(1);
      acc = __builtin_amdgcn_mfma_f32_16x16x32_bf16(ap0, bv0, acc, 0,0,0);
      acc = __builtin_amdgcn_mfma_f32_16x16x32_bf16(ap1, bv1, acc, 0,0,0);
      __builtin_amdgcn_s_setprio(0);
      const int mr = mbw + 4*lg;
      #pragma unroll
      for (int r = 0; r < 4; ++r)
        out[((size_t)b*S49 + mr + r)*D128 + vr] = acc[r]*inv[r];
    }
  }
}

extern "C" void kernel_launch(void* const* d_in, const int* in_sizes, int n_in,
                              void* d_out, int out_size, void* d_ws, size_t ws_size,
                              hipStream_t stream){
  const float* hs  = (const float*)d_in[0];
  const float* msk = (const float*)d_in[1];
  const float* Wq  = (const float*)d_in[2];
  const float* bq  = (const float*)d_in[3];
  const float* Wk  = (const float*)d_in[4];
  const float* bk  = (const float*)d_in[5];
  const float* Wv  = (const float*)d_in[6];
  const float* bv  = (const float*)d_in[7];
  const float* bt  = (const float*)d_in[8];
  unsigned short* wt = (unsigned short*)d_ws;
  float4* comb4 = (float4*)((char*)d_ws + 98304);
  float* out = (float*)d_out;
  const int B  = in_sizes[0] / (S49*D128);
  const int nW = in_sizes[1] / (S49*S49);
  prep_wt<<<dim3((3*128*128 + 255)/256), dim3(256), 0, stream>>>(Wq, Wk, Wv, wt);
  prep_comb<<<dim3((nW*NH*S49*16 + 255)/256), dim3(256), 0, stream>>>(msk, bt, comb4, nW);
  swin_attn<<<dim3(B), dim3(512), 0, stream>>>(hs, bq, bk, bv, comb4, wt, out, nW);
}

// Round 9
// 92.510 us; speedup vs baseline: 2.6350x; 1.1363x over previous
//
#include <hip/hip_runtime.h>
#include <hip/hip_bf16.h>

#define S49 49
#define D128 128
#define NH 4

typedef __attribute__((ext_vector_type(8))) short short8;
typedef __attribute__((ext_vector_type(4))) short short4v;
typedef __attribute__((ext_vector_type(4))) float f32x4;

__device__ __forceinline__ unsigned short f2b(float x){
  unsigned u = __builtin_bit_cast(unsigned, x);
  return (unsigned short)((u + 0x7fffu + ((u>>16)&1u)) >> 16);   // RNE
}
__device__ __forceinline__ unsigned pk2(float a, float b){
  __hip_bfloat162 h = __float22bfloat162_rn(float2{a, b});      // HW v_cvt_pk_bf16_f32
  unsigned u; __builtin_memcpy(&u, &h, 4);
  return u;
}
// XOR-swizzled LDS indexing (ushort units), 16B granule: conflict-free
// fragment reads at power-of-2 strides, no padding.
__device__ __forceinline__ int swz256i(int row, int col){  // 128-elem (256B) rows
  return row*128 + ((((col>>3) ^ (row&15)) << 3) | (col&7));
}

// ---- K0: transpose weights to Wt[mat][n][k] bf16 in workspace ----
__global__ void prep_wt(const float* __restrict__ Wq, const float* __restrict__ Wk,
                        const float* __restrict__ Wv, unsigned short* __restrict__ wt){
  int e = blockIdx.x*256 + threadIdx.x;
  if (e >= 3*128*128) return;
  int mat = e >> 14, rem = e & 16383, n = rem >> 7, k = rem & 127;
  const float* W = (mat==0) ? Wq : ((mat==1) ? Wk : Wv);
  wt[e] = f2b(W[k*128 + n]);
}

// ---- K1: combined (mask + rel-pos-bias) table, PRE-SCALED by log2(e), float4-swizzled ----
// comb4[(((w*NH+h)*49)+i)*16 + ln] = { c(i,ln), c(i,16+ln), c(i,32+ln), c(i,48+ln) } * log2e
// pad (j>=49) = -1e30 so exp2 -> 0 exactly.
__global__ void prep_comb(const float* __restrict__ mask, const float* __restrict__ bt,
                          float4* __restrict__ comb4, int nW){
  int e = blockIdx.x*256 + threadIdx.x;
  if (e >= nW*NH*S49*16) return;
  int ln = e & 15; int t = e >> 4;
  int i = t % S49; t /= S49;
  int h = t & (NH-1); int w = t / NH;
  const float* mrow = mask + ((size_t)w*S49 + i)*S49;
  int ri = i/7, ci = i - ri*7;
  const float L2E = 1.4426950408889634f;
  float v[4];
  #pragma unroll
  for (int nt = 0; nt < 4; ++nt){
    int j = nt*16 + ln;
    if (j < S49){
      int rj = j/7, cj = j - rj*7;
      int idx = (ri - rj + 6)*13 + (ci - cj + 6);
      v[nt] = (mrow[j] + bt[idx*NH + h]) * L2E;
    } else v[nt] = -1e30f;
  }
  float4 o; o.x = v[0]; o.y = v[1]; o.z = v[2]; o.w = v[3];
  comb4[e] = o;
}

// ---- main fused kernel: one block (8 waves) per window, 2 barriers ----
// LDS 53760B and (VGPR+AGPR)<=85 -> 3 blocks/CU (6 waves/EU). The mat-loop
// projection keeps the register peak inside the 512/6=85 budget (round 7's
// a[3][4] structure spilled under this bound; round 8 at (,4) allocated
// 64 VGPR + AGPRs > 85 and HW capped at 2 blocks).
__global__ __launch_bounds__(512, 6) void swin_attn(
    const float* __restrict__ hs,
    const float* __restrict__ bq, const float* __restrict__ bk,
    const float* __restrict__ bv,
    const float4* __restrict__ comb4,
    const unsigned short* __restrict__ wt, float* __restrict__ out, int nW){

  // 53664 B (rounds to 53760): hs/P 12544 | q 12544 | k 12544 | vt 14336 | pext 1696
  __shared__ __align__(16) unsigned short lds[26832];
  unsigned short* hs_s = lds;              // 49x128 swz256i; dead after proj -> P tiles waves 0..6
  unsigned short* q_s  = lds + 6272;       // 49x128 swz256i
  unsigned short* k_s  = lds + 12544;      // 49x128 swz256i (QK tile-3 rows reg-masked)
  unsigned short* vt_s = lds + 18816;      // 128x56 LINEAR (cols 49..55 zeroed; stride 112B = 2-way free)
  unsigned short* pext = lds + 25984;      // wave 7's P tile

  const int b = blockIdx.x;
  const int tid = threadIdx.x;
  const int wave = tid >> 6, lane = tid & 63;
  const int lg = lane >> 4, ln = lane & 15;
  unsigned short* pp = (wave < 7) ? (hs_s + wave*832) : pext;   // 16x52 linear per wave

  // ---- stage hidden_states f32 -> bf16 LDS ----
  const float* hsb = hs + (size_t)b * (S49*D128);
  #pragma unroll
  for (int it = 0; it < 4; ++it) {
    int u = tid + it*512;                  // 1568 units of 4 f32
    if (u < S49*32) {
      int row = u >> 5, c = u & 31;
      float4 f = *(const float4*)(hsb + row*128 + c*4);
      uint2 o; o.x = pk2(f.x, f.y); o.y = pk2(f.z, f.w);
      *(uint2*)&hs_s[swz256i(row, c*4)] = o;
    }
  }
  // zero vt cols 48..55 with one b128 per row (col 48 is rewritten by projection)
  if (tid < 128) {
    uint2 z2 = {0u,0u};
    *(uint2*)&vt_s[tid*56 + 48] = z2;
    *(uint2*)&vt_s[tid*56 + 52] = z2;
  }
  __syncthreads();

  const int w = b % nW;
  const int rt = wave & 3, hp = wave >> 2;
  const int mbw = (rt<3) ? rt*16 : 33;     // wave's q-row tile (overlap rows recompute identically)

  // ---- QKV projection: wave owns 16 output cols; Q,K,V processed sequentially ----
  {
    const int ntb = wave*16;
    #pragma unroll 1
    for (int mat = 0; mat < 3; ++mat) {
      short8 a[4];
      #pragma unroll
      for (int ks = 0; ks < 4; ++ks)
        a[ks] = *(const short8*)&wt[(mat<<14) + (ntb+ln)*128 + ks*32 + lg*8];
      const float* bp = (mat==0) ? bq : ((mat==1) ? bk : bv);
      float4 bias = *(const float4*)&bp[ntb + 4*lg];
      #pragma unroll
      for (int mt = 0; mt < 4; ++mt) {
        const int mb = (mt<3) ? mt*16 : 33;      // overlapping tiles cover rows 0..48
        short8 bh[4];
        #pragma unroll
        for (int ks = 0; ks < 4; ++ks)
          bh[ks] = *(const short8*)&hs_s[swz256i(mb+ln, ks*32 + lg*8)];
        f32x4 acc = {0.f,0.f,0.f,0.f};
        #pragma unroll
        for (int ks = 0; ks < 4; ++ks)
          acc = __builtin_amdgcn_mfma_f32_16x16x32_bf16(a[ks], bh[ks], acc, 0,0,0);
        // D transposed: col(ln) = token row m, rows(4lg+r) = output col n
        const int m = mb + ln;
        const int nb = ntb + 4*lg;
        if (mat == 0) {
          uint2 o; o.x = pk2(acc[0]+bias.x, acc[1]+bias.y);
                   o.y = pk2(acc[2]+bias.z, acc[3]+bias.w);
          *(uint2*)&q_s[swz256i(m, nb)] = o;
        } else if (mat == 1) {
          uint2 o; o.x = pk2(acc[0]+bias.x, acc[1]+bias.y);
                   o.y = pk2(acc[2]+bias.z, acc[3]+bias.w);
          *(uint2*)&k_s[swz256i(m, nb)] = o;
        } else {
          vt_s[(nb+0)*56 + m] = f2b(acc[0]+bias.x);
          vt_s[(nb+1)*56 + m] = f2b(acc[1]+bias.y);
          vt_s[(nb+2)*56 + m] = f2b(acc[2]+bias.z);
          vt_s[(nb+3)*56 + m] = f2b(acc[3]+bias.w);
        }
      }
    }
  }
  __syncthreads();
  // ---- attention: NO barriers (P wave-private; q/k/vt read-only; pp aliases dead hs) ----

  const float C1 = 0.17677669529663687f * 1.4426950408889634f;  // scale * log2e
  const short8 ones = {16256,16256,16256,16256,16256,16256,16256,16256};  // bf16 1.0
  const short4v z4 = {0,0,0,0};

  #pragma unroll
  for (int hh = 0; hh < 2; ++hh) {
    const int h = hp*2 + hh;
    float4 cb[4];
    #pragma unroll
    for (int r = 0; r < 4; ++r)
      cb[r] = comb4[((size_t)(w*NH + h)*S49 + mbw + 4*lg + r)*16 + ln];

    // ---- QK^T: k-tiles {0,16,32,48}; scores stay in registers ----
    short8 aq = *(const short8*)&q_s[swz256i(mbw+ln, h*32 + lg*8)];
    short8 kb[4];
    #pragma unroll
    for (int nt = 0; nt < 4; ++nt)
      kb[nt] = *(const short8*)&k_s[swz256i(nt*16+ln, h*32 + lg*8)];  // nt=3 ln>0: garbage rows
    if (ln != 0) kb[3] = short8{0,0,0,0,0,0,0,0};                     // only k-row 48 is real
    f32x4 s[4];
    __builtin_amdgcn_s_setprio(1);
    #pragma unroll
    for (int nt = 0; nt < 4; ++nt) {
      f32x4 z = {0.f,0.f,0.f,0.f};
      s[nt] = __builtin_amdgcn_mfma_f32_16x16x32_bf16(aq, kb[nt], z, 0,0,0);
    }
    __builtin_amdgcn_s_setprio(0);

    // ---- max-free softmax numerator; pad cols produce exactly 0 ----
    // lane holds q-rows (mbw+4lg+r), k = 16nt+ln
    #pragma unroll
    for (int r = 0; r < 4; ++r) {
      float cbv[4] = {cb[r].x, cb[r].y, cb[r].z, cb[r].w};
      #pragma unroll
      for (int nt = 0; nt < 4; ++nt) {
        float e = __builtin_amdgcn_exp2f(fmaf(s[nt][r], C1, cbv[nt]));
        if (nt < 3 || ln < 4)                       // P is 52 cols wide
          pp[(4*lg + r)*52 + nt*16 + ln] = f2b(e);
      }
    }

    // ---- P A-fragments (rows=q, k-cols) with pad masking ----
    short4v a0 = *(const short4v*)&pp[ln*52 + lg*8];
    short4v a1 = *(const short4v*)&pp[ln*52 + lg*8 + 4];
    short8 ap0 = __builtin_shufflevector(a0, a1, 0,1,2,3,4,5,6,7);
    short4v b0 = *(const short4v*)&pp[ln*52 + 32 + lg*8];
    short4v b1 = *(const short4v*)&pp[ln*52 + 36 + lg*8];
    if (lg >= 2) b1 = z4;                           // k 52..55 (garbage) / 60..63
    if (lg == 3) b0 = z4;                           // k 56..59
    short8 ap1 = __builtin_shufflevector(b0, b1, 0,1,2,3,4,5,6,7);

    // ---- row-sum via P @ ones, then P @ V; normalize at store ----
    f32x4 sacc = {0.f,0.f,0.f,0.f};
    __builtin_amdgcn_s_setprio(1);
    sacc = __builtin_amdgcn_mfma_f32_16x16x32_bf16(ap0, ones, sacc, 0,0,0);
    sacc = __builtin_amdgcn_mfma_f32_16x16x32_bf16(ap1, ones, sacc, 0,0,0);
    __builtin_amdgcn_s_setprio(0);
    float inv[4];
    #pragma unroll
    for (int r = 0; r < 4; ++r) inv[r] = __builtin_amdgcn_rcpf(sacc[r]);

    #pragma unroll
    for (int nt = 0; nt < 2; ++nt) {
      const int vr = h*32 + nt*16 + ln;             // output col == vt row
      short8 bv0 = *(const short8*)&vt_s[vr*56 + lg*8];
      short8 bv1 = {0,0,0,0,0,0,0,0};
      if (lg < 3) bv1 = *(const short8*)&vt_s[vr*56 + 32 + lg*8];  // lg=3 k>=56: masked (no NaN)
      f32x4 acc = {0.f,0.f,0.f,0.f};
      __builtin_amdgcn_s_setprio(1);
      acc = __builtin_amdgcn_mfma_f32_16x16x32_bf16(ap0, bv0, acc, 0,0,0);
      acc = __builtin_amdgcn_mfma_f32_16x16x32_bf16(ap1, bv1, acc, 0,0,0);
      __builtin_amdgcn_s_setprio(0);
      const int mr = mbw + 4*lg;
      #pragma unroll
      for (int r = 0; r < 4; ++r)
        out[((size_t)b*S49 + mr + r)*D128 + vr] = acc[r]*inv[r];
    }
  }
}

extern "C" void kernel_launch(void* const* d_in, const int* in_sizes, int n_in,
                              void* d_out, int out_size, void* d_ws, size_t ws_size,
                              hipStream_t stream){
  const float* hs  = (const float*)d_in[0];
  const float* msk = (const float*)d_in[1];
  const float* Wq  = (const float*)d_in[2];
  const float* bq  = (const float*)d_in[3];
  const float* Wk  = (const float*)d_in[4];
  const float* bk  = (const float*)d_in[5];
  const float* Wv  = (const float*)d_in[6];
  const float* bv  = (const float*)d_in[7];
  const float* bt  = (const float*)d_in[8];
  unsigned short* wt = (unsigned short*)d_ws;
  float4* comb4 = (float4*)((char*)d_ws + 98304);
  float* out = (float*)d_out;
  const int B  = in_sizes[0] / (S49*D128);
  const int nW = in_sizes[1] / (S49*S49);
  prep_wt<<<dim3((3*128*128 + 255)/256), dim3(256), 0, stream>>>(Wq, Wk, Wv, wt);
  prep_comb<<<dim3((nW*NH*S49*16 + 255)/256), dim3(256), 0, stream>>>(msk, bt, comb4, nW);
  swin_attn<<<dim3(B), dim3(512), 0, stream>>>(hs, bq, bk, bv, comb4, wt, out, nW);
}